// Round 6
// baseline (223.969 us; speedup 1.0000x reference)
//
#include <hip/hip_runtime.h>
#include <stdint.h>

// ReviewLoss: ce[i] = logsumexp(out[i,:]) - out[i, target[i]]
//   lam = k-th (0-indexed, descending) order statistic of ce, k = int(N*0.3)
//   result = mean over ALL N of (ce >= lam ? ce : 0)
//
// R5 post-mortem: OH ~125us fixed (harness ws-poison fill 76us + restore).
// ce + select ~ 85-95us vs ~30us floor. This round:
//  K1: fused ce + histogram. 512 blocks x 256 thr, 64 rows/block
//      (wave-per-row x 16). LDS 16384-bin packed hist (2 x u16 per u32,
//      key = u>>17 which is <= 16320 for any non-negative float), flushed
//      once per block to 8 global replicas (blockIdx&7) -> no hot-word
//      serialization (the R2 lesson).
//  K2: single-block selector: sum replicas -> hist -> (K, k'); ONE float4
//      pass over ce: sum keys>K, ballot-aggregated collect of key==K
//      candidates; exact lambda via level-2 packed hist (bits 17..4) +
//      level-3 16-bin hist (bits 3..0). No O(c^2) resolve, no hot counter.

typedef unsigned int uint32;

// ---------------- Kernel 1: CE + LDS histogram ----------------

__global__ __launch_bounds__(256) void ce_hist_kernel(
    const float* __restrict__ logits, const int* __restrict__ target,
    float* __restrict__ ce, uint32* __restrict__ ghist, int N, int C) {
  __shared__ uint32 lh[8192];  // 16384 packed u16 bins
  const int tid = (int)threadIdx.x;
  const int lane = tid & 63;
  const int wid = tid >> 6;

  for (int j = tid; j < 8192; j += 256) lh[j] = 0;
  __syncthreads();

  const float4 NEG = make_float4(-INFINITY, -INFINITY, -INFINITY, -INFINITY);
  const int nv4 = C >> 2;  // C % 4 == 0 (C=1000 -> 250 quads)
  const int rbase = (int)blockIdx.x * 64 + wid * 16;

  for (int r = 0; r < 16; ++r) {
    const int row = rbase + r;
    if (row >= N) break;  // wave-uniform
    const float* rp = logits + (size_t)row * (size_t)C;

    const int t = target[row];
    const float ot = rp[t];

    const float4* rp4 = (const float4*)rp;
    float4 v0 = (lane       < nv4) ? rp4[lane      ] : NEG;
    float4 v1 = (lane +  64 < nv4) ? rp4[lane +  64] : NEG;
    float4 v2 = (lane + 128 < nv4) ? rp4[lane + 128] : NEG;
    float4 v3 = (lane + 192 < nv4) ? rp4[lane + 192] : NEG;

    float m = fmaxf(fmaxf(fmaxf(v0.x, v0.y), fmaxf(v0.z, v0.w)),
                    fmaxf(fmaxf(fmaxf(v1.x, v1.y), fmaxf(v1.z, v1.w)),
                          fmaxf(fmaxf(fmaxf(v2.x, v2.y), fmaxf(v2.z, v2.w)),
                                fmaxf(fmaxf(v3.x, v3.y), fmaxf(v3.z, v3.w)))));
#pragma unroll
    for (int off = 1; off < 64; off <<= 1) m = fmaxf(m, __shfl_xor(m, off));

    float e = __expf(v0.x - m) + __expf(v0.y - m) + __expf(v0.z - m) + __expf(v0.w - m)
            + __expf(v1.x - m) + __expf(v1.y - m) + __expf(v1.z - m) + __expf(v1.w - m)
            + __expf(v2.x - m) + __expf(v2.y - m) + __expf(v2.z - m) + __expf(v2.w - m)
            + __expf(v3.x - m) + __expf(v3.y - m) + __expf(v3.z - m) + __expf(v3.w - m);
#pragma unroll
    for (int off = 1; off < 64; off <<= 1) e += __shfl_xor(e, off);

    if (lane == 0) {
      float cev = fmaxf((m - ot) + __logf(e), 0.0f);  // ce >= 0; kill -0.0
      ce[row] = cev;
      uint32 key = __float_as_uint(cev) >> 17;  // <= 16320 for cev >= 0
      atomicAdd(&lh[key >> 1], (key & 1u) ? 0x10000u : 1u);
    }
  }
  __syncthreads();

  // Flush nonzero words to this block's replica (block-aggregated adds).
  uint32* gh = ghist + (size_t)(blockIdx.x & 7) * 8192;
  for (int j = tid; j < 8192; j += 256) {
    uint32 w = lh[j];
    if (w) atomicAdd(&gh[j], w);
  }
}

// ---------------- Kernel 2: selection + filtered mean ----------------

// Find descending-rank `rank` in a 16384-bin packed hist H (8192 words).
// Uses g[1024] scratch; returns sel[0]=bin, sel[1]=rank-within-bin.
__device__ void find_level(uint32* H, uint32* g, uint32 rank, int tid,
                           volatile uint32* sel) {
  uint32 c = 0;
#pragma unroll
  for (int j = 0; j < 8; ++j) {
    uint32 w = H[8 * tid + j];
    c += (w & 0xFFFFu) + (w >> 16);
  }
  g[tid] = c;
  __syncthreads();
  // Inclusive suffix scan: g[t] = count(group >= t)
  for (int off = 1; off < 1024; off <<= 1) {
    uint32 v = g[tid] + ((tid + off < 1024) ? g[tid + off] : 0u);
    __syncthreads();
    g[tid] = v;
    __syncthreads();
  }
  uint32 SG = (tid + 1 < 1024) ? g[tid + 1] : 0u;
  if (SG <= rank && rank < g[tid]) { sel[0] = (uint32)tid; sel[1] = rank - SG; }
  __syncthreads();
  if (tid == 0) {
    uint32 grp = sel[0], kg = sel[1], acc = 0;
    for (int b = 15; b >= 0; --b) {
      uint32 bin = grp * 16u + (uint32)b;
      uint32 w = H[bin >> 1];
      uint32 cc = (bin & 1u) ? (w >> 16) : (w & 0xFFFFu);
      if (kg < acc + cc) { sel[0] = bin; sel[1] = kg - acc; break; }
      acc += cc;
    }
  }
  __syncthreads();
}

__global__ __launch_bounds__(1024) void select_kernel(
    const float* __restrict__ ce, const uint32* __restrict__ ghist,
    float* __restrict__ out, int N, int k) {
  __shared__ uint32 H[8192];     // packed hist (reused for level 2)
  __shared__ uint32 Cand[8192];  // candidate bit patterns
  __shared__ uint32 g[1024];
  __shared__ uint32 sel[2];
  __shared__ uint32 ccnt;
  __shared__ uint32 cnt16[16];
  __shared__ double wsum[16];
  const int tid = (int)threadIdx.x;
  const int lane = tid & 63;
  const float4* ce4 = (const float4*)ce;
  const int N4 = N >> 2;  // N % 4 == 0

  if (tid == 0) ccnt = 0;
  if (tid < 16) cnt16[tid] = 0;

  // ---- Sum the 8 replicas into LDS hist ----
  for (int j = tid; j < 8192; j += 1024) {
    uint32 w = 0;
#pragma unroll
    for (int r = 0; r < 8; ++r) w += ghist[(size_t)r * 8192 + j];
    H[j] = w;
  }
  __syncthreads();

  // ---- Level 1: lambda's 14-bit key K and rank within it ----
  find_level(H, g, (uint32)k, tid, sel);
  const uint32 K = sel[0];
  const uint32 kr1 = sel[1];
  __syncthreads();

  // ---- One pass over ce: sum key > K; ballot-collect key == K ----
  double acc = 0.0;
  const int iters = (N4 + 1023) / 1024;
  for (int it = 0; it < iters; ++it) {   // uniform trip count for ballots
    int i = it * 1024 + tid;
    float4 x;
    if (i < N4) x = ce4[i];
    else x = make_float4(-1.0f, -1.0f, -1.0f, -1.0f);  // key 0x7FC0.. no: sign=1 -> key>16320, never K; never >K sum? (-1 bits = 0xBF800000 -> key 0x5FC0 >16320? no)
    // Use explicit valid flag instead of sentinel values:
    bool valid = (i < N4);
    uint32 u[4];
    float f[4];
    f[0] = x.x; f[1] = x.y; f[2] = x.z; f[3] = x.w;
#pragma unroll
    for (int j = 0; j < 4; ++j) {
      u[j] = __float_as_uint(f[j]);
      uint32 key = u[j] >> 17;
      if (valid && key > K) acc += (double)f[j];
      bool mine = valid && (key == K);
      unsigned long long mk = __ballot(mine);
      uint32 cnt = (uint32)__popcll(mk);
      if (cnt) {
        int src = (int)__ffsll(mk) - 1;
        uint32 base = 0;
        if (lane == src) base = atomicAdd(&ccnt, cnt);
        base = (uint32)__shfl((int)base, src);
        if (mine) {
          uint32 p = base + (uint32)__popcll(mk & ((1ull << lane) - 1ull));
          if (p < 8192u) Cand[p] = u[j];
        }
      }
    }
  }
  __syncthreads();
  const uint32 c = (ccnt < 8192u) ? ccnt : 8192u;

  // ---- Level 2: packed hist over candidate bits 17..4 ----
  for (int j = tid; j < 8192; j += 1024) H[j] = 0;
  __syncthreads();
  for (uint32 j = (uint32)tid; j < c; j += 1024u) {
    uint32 key2 = (Cand[j] >> 4) & 0x3FFFu;
    atomicAdd(&H[key2 >> 1], (key2 & 1u) ? 0x10000u : 1u);
  }
  __syncthreads();
  find_level(H, g, kr1, tid, sel);
  const uint32 B2 = sel[0];
  const uint32 kr2 = sel[1];
  __syncthreads();

  // lambda bits 31..4 (bit 17 overlaps K/B2 consistently -> OR is fine)
  const uint32 lam_hi = (K << 17) | (B2 << 4);

  // ---- Level 3: 16-bin hist over bits 3..0 of exact-prefix candidates ----
  for (uint32 j = (uint32)tid; j < c; j += 1024u) {
    uint32 uj = Cand[j];
    if ((uj >> 4) == (lam_hi >> 4)) atomicAdd(&cnt16[uj & 15u], 1u);
  }
  __syncthreads();
  if (tid == 0) {
    uint32 kg = kr2, accu = 0;
    for (int b = 15; b >= 0; --b) {
      uint32 cc = cnt16[b];
      if (kg < accu + cc) { sel[0] = lam_hi | (uint32)b; break; }
      accu += cc;
    }
  }
  __syncthreads();
  const uint32 lam_u = sel[0];

  // ---- Add candidates >= lambda (ties included, matching ce>=lam keep) ----
  for (uint32 j = (uint32)tid; j < c; j += 1024u) {
    uint32 uj = Cand[j];
    if (uj >= lam_u) acc += (double)__uint_as_float(uj);
  }

  // ---- Reduce and write mean over all N ----
#pragma unroll
  for (int off = 1; off < 64; off <<= 1) acc += __shfl_xor(acc, off);
  if ((tid & 63) == 0) wsum[tid >> 6] = acc;
  __syncthreads();
  if (tid == 0) {
    double tsum = 0.0;
    for (int i = 0; i < 16; ++i) tsum += wsum[i];
    out[0] = (float)(tsum / (double)N);
  }
}

extern "C" void kernel_launch(void* const* d_in, const int* in_sizes, int n_in,
                              void* d_out, int out_size, void* d_ws, size_t ws_size,
                              hipStream_t stream) {
  const float* logits = (const float*)d_in[0];
  const int* target = (const int*)d_in[1];
  float* out = (float*)d_out;

  const int N = in_sizes[1];            // 32768
  const int C = in_sizes[0] / N;        // 1000

  float* ce = (float*)d_ws;
  uint32* ghist = (uint32*)((char*)d_ws + (size_t)N * sizeof(float));

  // Zero the 8 histogram replicas (ws is poisoned 0xAA each launch).
  hipMemsetAsync(ghist, 0, 8 * 8192 * sizeof(uint32), stream);

  // K1: fused CE + histogram. 64 rows per block.
  int grid = (N + 63) / 64;
  ce_hist_kernel<<<grid, 256, 0, stream>>>(logits, target, ce, ghist, N, C);

  // k = int(N * 0.3)
  int k = (int)((double)N * 0.3);

  // K2: single-block selection + filtered mean.
  select_kernel<<<1, 1024, 0, stream>>>(ce, ghist, out, N, k);
}